// Round 1
// baseline (167.847 us; speedup 1.0000x reference)
//
#include <hip/hip_runtime.h>

#define NN 256
#define HH 512
#define BB 128

// One-time prep: masked + transposed weights into workspace.
//   w0t[i*H + j] = (d_h[j] >= i)        ? w0[j*N + i] : 0     (N x H)
//   w1t[j*H + k] = (d_h[k] >= d_h[j])   ? w1[k*H + j] : 0     (H x H)
//   w2m[o*H + k] = (d_h[k] <  o % N)    ? w2[o*H + k] : 0     (2N x H)
__global__ void made_prep(const float* __restrict__ w0,
                          const float* __restrict__ w1,
                          const float* __restrict__ w2,
                          float* __restrict__ w0t,
                          float* __restrict__ w1t,
                          float* __restrict__ w2m) {
    int idx = blockIdx.x * blockDim.x + threadIdx.x;
    if (idx < NN * HH) {
        int i = idx >> 9, j = idx & (HH - 1);
        w0t[idx] = ((j % 255) >= i) ? w0[j * NN + i] : 0.f;
    }
    if (idx < HH * HH) {
        int j = idx >> 9, k = idx & (HH - 1);
        w1t[idx] = ((k % 255) >= (j % 255)) ? w1[k * HH + j] : 0.f;
    }
    if (idx < 2 * NN * HH) {
        int o = idx >> 9, k = idx & (HH - 1);
        int base = o & (NN - 1);
        w2m[idx] = ((k % 255) < base) ? w2[idx] : 0.f;
    }
}

// One block per batch element. 256 threads; thread t owns hidden units t and t+256.
// a0/a1 pre-activations live in registers. One __syncthreads per step
// (double-buffered LDS for reduce partials + level-i publish slots).
template <bool PRE>
__global__ __launch_bounds__(256)
void made_seq(const float* __restrict__ z,
              const float* __restrict__ w0, const float* __restrict__ b0,
              const float* __restrict__ w1, const float* __restrict__ b1,
              const float* __restrict__ w2, const float* __restrict__ b2,
              const float* __restrict__ w0t,
              const float* __restrict__ w1t,
              const float* __restrict__ w2m,
              float* __restrict__ out) {
    const int bb = blockIdx.x;
    const int t  = threadIdx.x;
    const int u0 = t, u1 = t + 256;
    const int l0 = u0 % 255, s0 = u0 / 255;   // level / publish-slot of unit u0
    const int l1 = u1 % 255, s1 = u1 / 255;
    const int wave = t >> 6, lane = t & 63;

    __shared__ float red[2][4][2];   // [buf][wave][{mu,al}]
    __shared__ float pub[2][3][2];   // [buf][slot][{a0_cur, w0_coef}]

    float a0_0 = b0[u0], a0_1 = b0[u1];
    float a1_0 = b1[u0], a1_1 = b1[u1];
    float ld = 0.f;

    // current-step weights (prefetched one step ahead)
    float cw2m0, cw2a0, cw2m1, cw2a1, cw00, cw01, cz;
    {
        const int i = 0;
        if (PRE) {
            cw2m0 = w2m[i * HH + u0]; cw2a0 = w2m[(NN + i) * HH + u0];
            cw2m1 = w2m[i * HH + u1]; cw2a1 = w2m[(NN + i) * HH + u1];
            cw00  = w0t[i * HH + u0]; cw01  = w0t[i * HH + u1];
        } else {
            cw2m0 = (l0 < i) ? w2[i * HH + u0] : 0.f;
            cw2a0 = (l0 < i) ? w2[(NN + i) * HH + u0] : 0.f;
            cw2m1 = (l1 < i) ? w2[i * HH + u1] : 0.f;
            cw2a1 = (l1 < i) ? w2[(NN + i) * HH + u1] : 0.f;
            cw00  = (l0 >= i) ? w0[u0 * NN + i] : 0.f;
            cw01  = (l1 >= i) ? w0[u1 * NN + i] : 0.f;
        }
        cz = z[bb * NN + 0];
    }

    for (int i = 0; i < NN; ++i) {
        const int ip = (i + 1 < NN) ? i + 1 : 0;  // prefetch index (wrap harmless)
        // ---- prefetch next step's w2/w0/z ----
        float nw2m0, nw2a0, nw2m1, nw2a1, nw00, nw01, nz;
        if (PRE) {
            nw2m0 = w2m[ip * HH + u0]; nw2a0 = w2m[(NN + ip) * HH + u0];
            nw2m1 = w2m[ip * HH + u1]; nw2a1 = w2m[(NN + ip) * HH + u1];
            nw00  = w0t[ip * HH + u0]; nw01  = w0t[ip * HH + u1];
        } else {
            nw2m0 = (l0 < ip) ? w2[ip * HH + u0] : 0.f;
            nw2a0 = (l0 < ip) ? w2[(NN + ip) * HH + u0] : 0.f;
            nw2m1 = (l1 < ip) ? w2[ip * HH + u1] : 0.f;
            nw2a1 = (l1 < ip) ? w2[(NN + ip) * HH + u1] : 0.f;
            nw00  = (l0 >= ip) ? w0[u0 * NN + ip] : 0.f;
            nw01  = (l1 >= ip) ? w0[u1 * NN + ip] : 0.f;
        }
        nz = z[bb * NN + ip];

        // ---- this step's w1 columns (levels i, i+255) ----
        float w1a0, w1a1, w1b0, w1b1;
        if (PRE) {
            w1a0 = w1t[i * HH + u0];         w1a1 = w1t[i * HH + u1];
            w1b0 = w1t[(i + 255) * HH + u0]; w1b1 = w1t[(i + 255) * HH + u1];
        } else {
            bool g0 = (l0 >= (i % 255)), g1 = (l1 >= (i % 255));
            w1a0 = g0 ? w1[u0 * HH + i] : 0.f;
            w1a1 = g1 ? w1[u1 * HH + i] : 0.f;
            w1b0 = g0 ? w1[u0 * HH + i + 255] : 0.f;
            w1b1 = g1 ? w1[u1 * HH + i + 255] : 0.f;
        }

        // ---- phase 1: masked dots for mu/alpha ----
        float h10 = fmaxf(a1_0, 0.f), h11 = fmaxf(a1_1, 0.f);
        float pm = h10 * cw2m0 + h11 * cw2m1;
        float pa = h10 * cw2a0 + h11 * cw2a1;
        #pragma unroll
        for (int off = 32; off > 0; off >>= 1) {
            pm += __shfl_xor(pm, off);
            pa += __shfl_xor(pa, off);
        }
        const int bf = i & 1;
        if (lane == 0) { red[bf][wave][0] = pm; red[bf][wave][1] = pa; }
        // publish level-i units' (a0, w0-coef) so h0 can be formed after x_i known
        if (l0 == i) { pub[bf][s0][0] = a0_0; pub[bf][s0][1] = cw00; }
        if (l1 == i) { pub[bf][s1][0] = a0_1; pub[bf][s1][1] = cw01; }
        __syncthreads();

        // ---- all threads: finish reduce, compute x_i redundantly ----
        float mu = b2[i]      + red[bf][0][0] + red[bf][1][0] + red[bf][2][0] + red[bf][3][0];
        float al = b2[NN + i] + red[bf][0][1] + red[bf][1][1] + red[bf][2][1] + red[bf][3][1];
        ld += al;
        float xi = fmaf(cz, __expf(al), mu);
        if (t == 0) out[bb * NN + i] = xi;

        // ---- phase B: rank-1 update of a0 with x_i ----
        a0_0 = fmaf(xi, cw00, a0_0);
        a0_1 = fmaf(xi, cw01, a0_1);

        // ---- phase C: propagate level-i h0 into a1 ----
        float h0a = fmaxf(fmaf(xi, pub[bf][0][1], pub[bf][0][0]), 0.f);
        float h0b = fmaxf(fmaf(xi, pub[bf][1][1], pub[bf][1][0]), 0.f);
        a1_0 = fmaf(h0a, w1a0, a1_0);
        a1_1 = fmaf(h0a, w1a1, a1_1);
        a1_0 = fmaf(h0b, w1b0, a1_0);
        a1_1 = fmaf(h0b, w1b1, a1_1);
        if (i < 2) {  // third unit at levels 0,1 only (units 510,511)
            float w1c0, w1c1;
            if (PRE) {
                w1c0 = w1t[(i + 510) * HH + u0];
                w1c1 = w1t[(i + 510) * HH + u1];
            } else {
                w1c0 = (l0 >= i) ? w1[u0 * HH + i + 510] : 0.f;
                w1c1 = (l1 >= i) ? w1[u1 * HH + i + 510] : 0.f;
            }
            float h0c = fmaxf(fmaf(xi, pub[bf][2][1], pub[bf][2][0]), 0.f);
            a1_0 = fmaf(h0c, w1c0, a1_0);
            a1_1 = fmaf(h0c, w1c1, a1_1);
        }

        cw2m0 = nw2m0; cw2a0 = nw2a0; cw2m1 = nw2m1; cw2a1 = nw2a1;
        cw00 = nw00; cw01 = nw01; cz = nz;
    }

    if (t == 0) out[BB * NN + bb] = -ld;   // second output: -log_det
}

extern "C" void kernel_launch(void* const* d_in, const int* in_sizes, int n_in,
                              void* d_out, int out_size, void* d_ws, size_t ws_size,
                              hipStream_t stream) {
    const float* z  = (const float*)d_in[0];
    const float* w0 = (const float*)d_in[1];
    const float* b0 = (const float*)d_in[2];
    const float* w1 = (const float*)d_in[3];
    const float* b1 = (const float*)d_in[4];
    const float* w2 = (const float*)d_in[5];
    const float* b2 = (const float*)d_in[6];
    float* out = (float*)d_out;

    const size_t need = (size_t)(NN * HH + HH * HH + 2 * NN * HH) * sizeof(float);
    if (ws_size >= need) {
        float* w0t = (float*)d_ws;
        float* w1t = w0t + NN * HH;
        float* w2m = w1t + HH * HH;
        made_prep<<<(2 * NN * HH + 255) / 256, 256, 0, stream>>>(w0, w1, w2, w0t, w1t, w2m);
        made_seq<true><<<BB, 256, 0, stream>>>(z, w0, b0, w1, b1, w2, b2,
                                               w0t, w1t, w2m, out);
    } else {
        made_seq<false><<<BB, 256, 0, stream>>>(z, w0, b0, w1, b1, w2, b2,
                                                nullptr, nullptr, nullptr, out);
    }
}

// Round 2
// 79.483 us; speedup vs baseline: 2.1117x; 2.1117x over previous
//
#include <hip/hip_runtime.h>

#define NN 256
#define HH 512
#define BB 128

// ---------------- prep: masked + transposed weights into workspace ----------
//   w0t[i*H + j] = (d_h[j] >= i)        ? w0[j*N + i] : 0     (N x H)
//   w1t[j*H + k] = (d_h[k] >= d_h[j])   ? w1[k*H + j] : 0     (H x H)
//   w2m[o*H + k] = (d_h[k] <  o % N)    ? w2[o*H + k] : 0     (2N x H)
__global__ void made_prep(const float* __restrict__ w0,
                          const float* __restrict__ w1,
                          const float* __restrict__ w2,
                          float* __restrict__ w0t,
                          float* __restrict__ w1t,
                          float* __restrict__ w2m) {
    int idx = blockIdx.x * blockDim.x + threadIdx.x;
    if (idx < NN * HH) {
        int i = idx >> 9, j = idx & (HH - 1);
        w0t[idx] = ((j % 255) >= i) ? w0[j * NN + i] : 0.f;
    }
    if (idx < HH * HH) {
        int j = idx >> 9, k = idx & (HH - 1);
        w1t[idx] = ((k % 255) >= (j % 255)) ? w1[k * HH + j] : 0.f;
    }
    if (idx < 2 * NN * HH) {
        int o = idx >> 9, k = idx & (HH - 1);
        int base = o & (NN - 1);
        w2m[idx] = ((k % 255) < base) ? w2[idx] : 0.f;
    }
}

// ---------------- single-wave sequential kernel -----------------------------
struct R8 { float v[8]; };

__device__ __forceinline__ void ld8(R8& d, const float* __restrict__ p, int off) {
    float4 a = *(const float4*)(p + off);
    float4 b = *(const float4*)(p + off + 4);
    d.v[0] = a.x; d.v[1] = a.y; d.v[2] = a.z; d.v[3] = a.w;
    d.v[4] = b.x; d.v[5] = b.y; d.v[6] = b.z; d.v[7] = b.w;
}

__device__ __forceinline__ float rl_f(float v, int lane) {
    return __int_as_float(__builtin_amdgcn_readlane(__float_as_int(v), lane));
}

// one DPP-assisted add step: v += dpp_move(v) with identity(0) fill
#define DPP_ADD(v, ctrl, rm) \
    ((v) + __int_as_float(__builtin_amdgcn_update_dpp(0, __float_as_int(v), (ctrl), (rm), 0xf, false)))

// full-wave (64-lane) sum of pm and pa; totals end up in lane 63
__device__ __forceinline__ void reduce2(float& pm, float& pa) {
    pm = DPP_ADD(pm, 0x111, 0xf);  pa = DPP_ADD(pa, 0x111, 0xf);  // row_shr:1
    pm = DPP_ADD(pm, 0x112, 0xf);  pa = DPP_ADD(pa, 0x112, 0xf);  // row_shr:2
    pm = DPP_ADD(pm, 0x114, 0xf);  pa = DPP_ADD(pa, 0x114, 0xf);  // row_shr:4
    pm = DPP_ADD(pm, 0x118, 0xf);  pa = DPP_ADD(pa, 0x118, 0xf);  // row_shr:8
    pm = DPP_ADD(pm, 0x142, 0xa);  pa = DPP_ADD(pa, 0x142, 0xa);  // row_bcast15 -> rows 1,3
    pm = DPP_ADD(pm, 0x143, 0xc);  pa = DPP_ADD(pa, 0x143, 0xc);  // row_bcast31 -> rows 2,3
}

// One 64-thread wave per batch element. Lane t owns units 8t..8t+7.
// a0/a1 in registers; reductions via DPP; publishes via v_readlane.
// No LDS, no __syncthreads.
__global__ __launch_bounds__(64)
void made_seq64(const float* __restrict__ z,
                const float* __restrict__ b0g,
                const float* __restrict__ b1g,
                const float* __restrict__ b2g,
                const float* __restrict__ w0t,
                const float* __restrict__ w1t,
                const float* __restrict__ w2m,
                float* __restrict__ out) {
    const int bb  = blockIdx.x;
    const int t   = threadIdx.x;
    const int off = t << 3;

    R8 a0, a1, b2r;
    ld8(a0,  b0g, off);
    ld8(a1,  b1g, off);
    ld8(b2r, b2g, off);                       // lane t holds b2[8t..8t+7]
    float4 z4 = *(const float4*)(z + bb * NN + (t << 2));
    float zr[4] = {z4.x, z4.y, z4.z, z4.w};   // lane t holds z[4t..4t+3]

    R8 w1c0, w1c1;                            // w1 rows for units 510, 511
    ld8(w1c0, w1t + (size_t)510 * HH, off);
    ld8(w1c1, w1t + (size_t)511 * HH, off);

    // double-buffered weight rows (parity = step & 1)
    R8 bw2m[2], bw2a[2], bw0[2], bw1a[2], bw1b[2];
    ld8(bw2m[0], w2m, off);
    ld8(bw2a[0], w2m + (size_t)NN * HH, off);
    ld8(bw0 [0], w0t, off);
    ld8(bw1a[0], w1t, off);
    ld8(bw1b[0], w1t + (size_t)255 * HH, off);

    float ld = 0.f;

    for (int g = 0; g < 32; ++g) {
        #pragma unroll
        for (int r = 0; r < 8; ++r) {          // r is compile-time after unroll
            const int cur = r & 1, nxt = cur ^ 1;
            const int i   = (g << 3) | r;
            const int ipn = (i + 1) & 255;     // wrap at 255 -> dummy row 0

            // ---- prefetch next step's weight rows ----
            ld8(bw2m[nxt], w2m + (size_t)ipn * HH, off);
            ld8(bw2a[nxt], w2m + (size_t)(NN + ipn) * HH, off);
            ld8(bw0 [nxt], w0t + (size_t)ipn * HH, off);
            ld8(bw1a[nxt], w1t + (size_t)ipn * HH, off);
            ld8(bw1b[nxt], w1t + (size_t)(ipn + 255) * HH, off);

            // ---- masked dots for mu/alpha (tree form) ----
            float h[8];
            #pragma unroll
            for (int j = 0; j < 8; ++j) h[j] = fmaxf(a1.v[j], 0.f);

            float pm01 = fmaf(h[1], bw2m[cur].v[1], h[0] * bw2m[cur].v[0]);
            float pm23 = fmaf(h[3], bw2m[cur].v[3], h[2] * bw2m[cur].v[2]);
            float pm45 = fmaf(h[5], bw2m[cur].v[5], h[4] * bw2m[cur].v[4]);
            float pm67 = fmaf(h[7], bw2m[cur].v[7], h[6] * bw2m[cur].v[6]);
            float pm   = (pm01 + pm23) + (pm45 + pm67);

            float pa01 = fmaf(h[1], bw2a[cur].v[1], h[0] * bw2a[cur].v[0]);
            float pa23 = fmaf(h[3], bw2a[cur].v[3], h[2] * bw2a[cur].v[2]);
            float pa45 = fmaf(h[5], bw2a[cur].v[5], h[4] * bw2a[cur].v[4]);
            float pa67 = fmaf(h[7], bw2a[cur].v[7], h[6] * bw2a[cur].v[6]);
            float pa   = (pa01 + pa23) + (pa45 + pa67);

            reduce2(pm, pa);
            float tm = rl_f(pm, 63);
            float ta = rl_f(pa, 63);

            // ---- publish level-i units (pre-update a0 + this step's w0 coef)
            // unit i      : lane g,      slot r
            // unit i+255  : lane LB,     slot sB
            const int sB = (r + 7) & 7;
            const int LB = (r == 0) ? (g + 31) : (g + 32);
            float a0A = rl_f(a0.v[r],          g);
            float w0A = rl_f(bw0[cur].v[r],    g);
            float a0B = rl_f(a0.v[sB],         LB);
            float w0B = rl_f(bw0[cur].v[sB],   LB);

            // ---- x_i ----
            float mu = tm + rl_f(b2r.v[r], g);
            float al = ta + rl_f(b2r.v[r], g + 32);
            ld += al;
            float zi = rl_f(zr[r & 3], (g << 1) + (r >> 2));
            float xi = fmaf(zi, __expf(al), mu);
            if (t == 0) out[(bb << 8) | i] = xi;

            float h0a = fmaxf(fmaf(xi, w0A, a0A), 0.f);
            float h0b = fmaxf(fmaf(xi, w0B, a0B), 0.f);

            // third published unit: 510 at i=0, 511 at i=1 (lane 63, slot 6+r)
            if (r < 2) {
                if (g == 0) {
                    float a0C = rl_f(a0.v[6 + r],       63);
                    float w0C = rl_f(bw0[cur].v[6 + r], 63);
                    float h0c = fmaxf(fmaf(xi, w0C, a0C), 0.f);
                    const R8& wc = (r == 0) ? w1c0 : w1c1;
                    #pragma unroll
                    for (int j = 0; j < 8; ++j)
                        a1.v[j] = fmaf(h0c, wc.v[j], a1.v[j]);
                }
            }

            // ---- rank-1 updates ----
            #pragma unroll
            for (int j = 0; j < 8; ++j)
                a0.v[j] = fmaf(xi, bw0[cur].v[j], a0.v[j]);
            #pragma unroll
            for (int j = 0; j < 8; ++j)
                a1.v[j] = fmaf(h0b, bw1b[cur].v[j], fmaf(h0a, bw1a[cur].v[j], a1.v[j]));
        }
    }

    if (t == 0) out[BB * NN + bb] = -ld;
}

// ---------------- fallback (no workspace): previous verified kernel ---------
__global__ __launch_bounds__(256)
void made_seq_fb(const float* __restrict__ z,
                 const float* __restrict__ w0, const float* __restrict__ b0,
                 const float* __restrict__ w1, const float* __restrict__ b1,
                 const float* __restrict__ w2, const float* __restrict__ b2,
                 float* __restrict__ out) {
    const int bb = blockIdx.x;
    const int t  = threadIdx.x;
    const int u0 = t, u1 = t + 256;
    const int l0 = u0 % 255, s0 = u0 / 255;
    const int l1 = u1 % 255, s1 = u1 / 255;
    const int wave = t >> 6, lane = t & 63;

    __shared__ float red[2][4][2];
    __shared__ float pub[2][3][2];

    float a0_0 = b0[u0], a0_1 = b0[u1];
    float a1_0 = b1[u0], a1_1 = b1[u1];
    float ld = 0.f;

    for (int i = 0; i < NN; ++i) {
        float cw2m0 = (l0 < i) ? w2[i * HH + u0] : 0.f;
        float cw2a0 = (l0 < i) ? w2[(NN + i) * HH + u0] : 0.f;
        float cw2m1 = (l1 < i) ? w2[i * HH + u1] : 0.f;
        float cw2a1 = (l1 < i) ? w2[(NN + i) * HH + u1] : 0.f;
        float cw00  = (l0 >= i) ? w0[u0 * NN + i] : 0.f;
        float cw01  = (l1 >= i) ? w0[u1 * NN + i] : 0.f;
        bool g0 = (l0 >= (i % 255)), g1 = (l1 >= (i % 255));
        float w1a0 = g0 ? w1[u0 * HH + i] : 0.f;
        float w1a1 = g1 ? w1[u1 * HH + i] : 0.f;
        float w1b0 = g0 ? w1[u0 * HH + i + 255] : 0.f;
        float w1b1 = g1 ? w1[u1 * HH + i + 255] : 0.f;

        float h10 = fmaxf(a1_0, 0.f), h11 = fmaxf(a1_1, 0.f);
        float pm = h10 * cw2m0 + h11 * cw2m1;
        float pa = h10 * cw2a0 + h11 * cw2a1;
        #pragma unroll
        for (int offs = 32; offs > 0; offs >>= 1) {
            pm += __shfl_xor(pm, offs);
            pa += __shfl_xor(pa, offs);
        }
        const int bf = i & 1;
        if (lane == 0) { red[bf][wave][0] = pm; red[bf][wave][1] = pa; }
        if (l0 == i) { pub[bf][s0][0] = a0_0; pub[bf][s0][1] = cw00; }
        if (l1 == i) { pub[bf][s1][0] = a0_1; pub[bf][s1][1] = cw01; }
        __syncthreads();

        float mu = b2[i]      + red[bf][0][0] + red[bf][1][0] + red[bf][2][0] + red[bf][3][0];
        float al = b2[NN + i] + red[bf][0][1] + red[bf][1][1] + red[bf][2][1] + red[bf][3][1];
        ld += al;
        float xi = fmaf(z[bb * NN + i], __expf(al), mu);
        if (t == 0) out[bb * NN + i] = xi;

        a0_0 = fmaf(xi, cw00, a0_0);
        a0_1 = fmaf(xi, cw01, a0_1);

        float h0a = fmaxf(fmaf(xi, pub[bf][0][1], pub[bf][0][0]), 0.f);
        float h0b = fmaxf(fmaf(xi, pub[bf][1][1], pub[bf][1][0]), 0.f);
        a1_0 = fmaf(h0a, w1a0, a1_0);
        a1_1 = fmaf(h0a, w1a1, a1_1);
        a1_0 = fmaf(h0b, w1b0, a1_0);
        a1_1 = fmaf(h0b, w1b1, a1_1);
        if (i < 2) {
            float w1c0 = (l0 >= i) ? w1[u0 * HH + i + 510] : 0.f;
            float w1c1 = (l1 >= i) ? w1[u1 * HH + i + 510] : 0.f;
            float h0c = fmaxf(fmaf(xi, pub[bf][2][1], pub[bf][2][0]), 0.f);
            a1_0 = fmaf(h0c, w1c0, a1_0);
            a1_1 = fmaf(h0c, w1c1, a1_1);
        }
        __syncthreads();
    }

    if (t == 0) out[BB * NN + bb] = -ld;
}

extern "C" void kernel_launch(void* const* d_in, const int* in_sizes, int n_in,
                              void* d_out, int out_size, void* d_ws, size_t ws_size,
                              hipStream_t stream) {
    const float* z  = (const float*)d_in[0];
    const float* w0 = (const float*)d_in[1];
    const float* b0 = (const float*)d_in[2];
    const float* w1 = (const float*)d_in[3];
    const float* b1 = (const float*)d_in[4];
    const float* w2 = (const float*)d_in[5];
    const float* b2 = (const float*)d_in[6];
    float* out = (float*)d_out;

    const size_t need = (size_t)(NN * HH + HH * HH + 2 * NN * HH) * sizeof(float);
    if (ws_size >= need) {
        float* w0t = (float*)d_ws;
        float* w1t = w0t + NN * HH;
        float* w2m = w1t + HH * HH;
        made_prep<<<(2 * NN * HH + 255) / 256, 256, 0, stream>>>(w0, w1, w2, w0t, w1t, w2m);
        made_seq64<<<BB, 64, 0, stream>>>(z, b0, b1, b2, w0t, w1t, w2m, out);
    } else {
        made_seq_fb<<<BB, 256, 0, stream>>>(z, w0, b0, w1, b1, w2, b2, out);
    }
}